// Round 8
// baseline (466.419 us; speedup 1.0000x reference)
//
#include <hip/hip_runtime.h>
#include <hip/hip_bf16.h>
#include <float.h>
#include <math.h>

#define NB 32
#define NS 4096
#define NE 1024
#define ND 1024
#define NA 512

typedef __attribute__((ext_vector_type(4))) float f32x4;
typedef __attribute__((ext_vector_type(8))) short short8;

static __device__ __forceinline__ ushort f2bf(float f){
    union { float f; unsigned int u; } x; x.f = f;
    unsigned int u = x.u + 0x7fffu + ((x.u >> 16) & 1u);
    return (ushort)(u >> 16);
}

static __device__ __forceinline__ float tanh_fast(float x){
    float e = __expf(2.f * x);
    return 1.f - 2.f / (e + 1.f);
}

// ---- K1a: W_h (1024x512 f32) -> WTf bf16 in MFMA-fragment order ----
__global__ __launch_bounds__(256) void k_prep_wtf(const float* __restrict__ Wh,
                                                  ushort* __restrict__ WTf){
    int i = blockIdx.x * 256 + threadIdx.x;   // 524288 outputs
    int e = i & 7;
    int lane = (i >> 3) & 63;
    int ng = (i >> 9) & 31;
    int s = i >> 14;
    int k = s * 32 + (lane >> 4) * 8 + e;
    int col = ng * 16 + (lane & 15);
    WTf[i] = f2bf(Wh[k * NA + col]);
}

// ---- K1b: proj_dec partials ----
__global__ __launch_bounds__(512) void k_projdec(const float* __restrict__ dec,
                                                 const float* __restrict__ Ws,
                                                 float* __restrict__ pdp){
    int b = blockIdx.x >> 2, kc = blockIdx.x & 3;
    int a = threadIdx.x;
    const float* dp = dec + b * ND + kc * 256;
    const float* wp = Ws + (size_t)(kc * 256) * NA + a;
    float acc = 0.f;
    #pragma unroll 4
    for (int k = 0; k < 256; k++) acc += dp[k] * wp[(size_t)k * NA];
    pdp[(kc * NB + b) * NA + a] = acc;
}

// ---- K2: fused scores GEMM, 8-phase schedule (T3+T4+T5+T14). ----
// BM=256, BN=256 (bn half), BK=64, 8 waves (2M x 4N), wave-tile 128x64, acc[8][4].
// Per K-step: wt L2 loads (oldest) -> all 8 stage HBM loads -> 4 phases of
// {ds_read 4 A-frags -> barrier -> setprio(1) -> 16 MFMA -> setprio(0) ->
//  [p3: stage_write] -> lgkmcnt(0) -> barrier}.
__global__ __launch_bounds__(512, 2) void k_scores(const float* __restrict__ E,
                                                   const ushort* __restrict__ WTf,
                                                   const float* __restrict__ pdp,
                                                   const float* __restrict__ v,
                                                   float* __restrict__ scrp){
    const int t = threadIdx.x;
    const int lane = t & 63, w = t >> 6;
    const int l15 = lane & 15, grp = lane >> 4;
    const int wm = w >> 2, wn = w & 3;

    // XCD-major mapping: 1024 blocks, bn-halves of one m-tile adjacent.
    const int bid = blockIdx.x;
    const int xcd = bid & 7, slot = bid >> 3;
    const int mblk = xcd * 64 + (slot >> 1);  // 0..511
    const int bn = slot & 1;
    const int m0 = mblk << 8;                 // 256-row base
    const int b = mblk >> 4;                  // batch

    __shared__ __align__(16) ushort bft[2][256 * 64];  // 2 x 32KB bf16 E-tiles (swizzled)
    __shared__ float sc[256][4];

    // staging: thread -> row sr = t>>1 (0..255), half = t&1 (32 floats)
    const int sr = t >> 1, half = t & 1;
    const float* gsrc = E + (size_t)(m0 + sr) * NE + half * 32;

    f32x4 acc[8][4];
    f32x4 zero; zero[0]=0.f; zero[1]=0.f; zero[2]=0.f; zero[3]=0.f;
    #pragma unroll
    for (int m = 0; m < 8; m++)
        #pragma unroll
        for (int n = 0; n < 4; n++) acc[m][n] = zero;

    f32x4 st[8];
    auto stage_load = [&](int it){
        const f32x4* p = (const f32x4*)(gsrc + it * 64);
        st[0]=p[0]; st[1]=p[1]; st[2]=p[2]; st[3]=p[3];
        st[4]=p[4]; st[5]=p[5]; st[6]=p[6]; st[7]=p[7];
    };
    auto stage_write = [&](int buf){
        char* bb = (char*)&bft[buf][0];
        #pragma unroll
        for (int q = 0; q < 4; ++q){
            short8 h;
            #pragma unroll
            for (int e = 0; e < 4; e++){
                h[e]     = (short)__builtin_bit_cast(ushort, __float2bfloat16(st[2*q][e]));
                h[e + 4] = (short)__builtin_bit_cast(ushort, __float2bfloat16(st[2*q+1][e]));
            }
            unsigned g = (unsigned)(half * 4 + q);
            *(short8*)(bb + sr * 128 + ((g ^ (unsigned)(sr & 7)) << 4)) = h;
        }
    };

    // B-frag base: slice s = it*2+kk at +s*16384 ushorts; frag n at +n*512
    const ushort* wtf0 = WTf + ((size_t)(bn * 16 + wn * 4) * 64 + lane) * 8;

    // prologue
    stage_load(0);
    stage_write(0);
    asm volatile("s_waitcnt lgkmcnt(0)" ::: "memory");
    __builtin_amdgcn_s_barrier();

    for (int it = 0; it < 16; ++it){
        const int buf = it & 1;
        const char* base = (const char*)&bft[buf][0];

        // wt loads for both kk (OLDEST in vmem queue this iter)
        short8 wt0[4], wt1[4];
        const ushort* wp0 = wtf0 + (size_t)(it * 2) * 16384;
        #pragma unroll
        for (int n = 0; n < 4; n++) wt0[n] = *(const short8*)(wp0 + n * 512);
        #pragma unroll
        for (int n = 0; n < 4; n++) wt1[n] = *(const short8*)(wp0 + 16384 + n * 512);
        __builtin_amdgcn_sched_barrier(0);
        // next-tile HBM loads (NEWER; in flight ~3 phases before stage_write)
        if (it < 15) stage_load(it + 1);
        __builtin_amdgcn_sched_barrier(0);

        #pragma unroll
        for (int p = 0; p < 4; ++p){
            // this phase's A-frags: m-frags 2p, 2p+1, both kk
            short8 a0k0, a0k1, a1k0, a1k1;
            {
                const int r0 = wm * 128 + (2*p)     * 16 + l15;
                const int r1 = wm * 128 + (2*p + 1) * 16 + l15;
                a0k0 = *(const short8*)(base + r0 * 128 + (((0u * 4 + grp) ^ (unsigned)(r0 & 7)) << 4));
                a0k1 = *(const short8*)(base + r0 * 128 + (((1u * 4 + grp) ^ (unsigned)(r0 & 7)) << 4));
                a1k0 = *(const short8*)(base + r1 * 128 + (((0u * 4 + grp) ^ (unsigned)(r1 & 7)) << 4));
                a1k1 = *(const short8*)(base + r1 * 128 + (((1u * 4 + grp) ^ (unsigned)(r1 & 7)) << 4));
            }
            __builtin_amdgcn_s_barrier();
            __builtin_amdgcn_s_setprio(1);
            #pragma unroll
            for (int n = 0; n < 4; n++){
                acc[2*p  ][n] = __builtin_amdgcn_mfma_f32_16x16x32_bf16(a0k0, wt0[n], acc[2*p  ][n], 0, 0, 0);
                acc[2*p  ][n] = __builtin_amdgcn_mfma_f32_16x16x32_bf16(a0k1, wt1[n], acc[2*p  ][n], 0, 0, 0);
                acc[2*p+1][n] = __builtin_amdgcn_mfma_f32_16x16x32_bf16(a1k0, wt0[n], acc[2*p+1][n], 0, 0, 0);
                acc[2*p+1][n] = __builtin_amdgcn_mfma_f32_16x16x32_bf16(a1k1, wt1[n], acc[2*p+1][n], 0, 0, 0);
            }
            __builtin_amdgcn_s_setprio(0);
            if (p == 3 && it < 15) stage_write(buf ^ 1);   // vmcnt-counted wait on st
            asm volatile("s_waitcnt lgkmcnt(0)" ::: "memory");
            __builtin_amdgcn_sched_barrier(0);
            __builtin_amdgcn_s_barrier();
        }
    }

    // epilogue: +proj_dec, fast-tanh, v-dot, reduce over this block's 256 cols
    float pdc[4], vc[4];
    #pragma unroll
    for (int n = 0; n < 4; n++){
        int c = bn * 256 + wn * 64 + n * 16 + l15;
        float p = 0.f;
        #pragma unroll
        for (int kc = 0; kc < 4; kc++) p += pdp[(kc * NB + b) * NA + c];
        pdc[n] = p;
        vc[n] = v[c];
    }
    #pragma unroll
    for (int m = 0; m < 8; m++){
        #pragma unroll
        for (int j = 0; j < 4; j++){
            float s = 0.f;
            #pragma unroll
            for (int n = 0; n < 4; n++) s += tanh_fast(acc[m][n][j] + pdc[n]) * vc[n];
            s += __shfl_xor(s, 1);
            s += __shfl_xor(s, 2);
            s += __shfl_xor(s, 4);
            s += __shfl_xor(s, 8);
            if (l15 == 0) sc[wm * 128 + m * 16 + grp * 4 + j][wn] = s;
        }
    }
    __syncthreads();
    if (t < 256)
        scrp[(size_t)bn * (NB * NS) + m0 + t] = sc[t][0] + sc[t][1] + sc[t][2] + sc[t][3];
}

// ---- K3: masked softmax; sums the two N-half score partials ----
__global__ __launch_bounds__(256) void k_softmax(const float* __restrict__ scrp,
                                                 const int* __restrict__ mask,
                                                 float* __restrict__ weights){
    int b = blockIdx.x, t = threadIdx.x;
    __shared__ float red[8];
    float vals[16];
    float mx = -FLT_MAX;
    #pragma unroll
    for (int i = 0; i < 16; i++){
        int s = i * 256 + t;
        float x = scrp[b * NS + s] + scrp[(size_t)(NB * NS) + b * NS + s];
        x = (mask[b * NS + s] != 0) ? x : -FLT_MAX;
        vals[i] = x;
        mx = fmaxf(mx, x);
    }
    #pragma unroll
    for (int off = 32; off; off >>= 1) mx = fmaxf(mx, __shfl_xor(mx, off));
    int wv = t >> 6;
    if ((t & 63) == 0) red[wv] = mx;
    __syncthreads();
    mx = fmaxf(fmaxf(red[0], red[1]), fmaxf(red[2], red[3]));
    float sum = 0.f;
    #pragma unroll
    for (int i = 0; i < 16; i++){ vals[i] = __expf(vals[i] - mx); sum += vals[i]; }
    #pragma unroll
    for (int off = 32; off; off >>= 1) sum += __shfl_xor(sum, off);
    if ((t & 63) == 0) red[4 + wv] = sum;
    __syncthreads();
    sum = red[4] + red[5] + red[6] + red[7];
    float inv = 1.f / sum;
    #pragma unroll
    for (int i = 0; i < 16; i++) weights[b * NS + i * 256 + t] = vals[i] * inv;
}

// ---- K4: context partials over S-chunks ----
__global__ __launch_bounds__(1024) void k_context(const float* __restrict__ E,
                                                  const float* __restrict__ weights,
                                                  float* __restrict__ part){
    int b = blockIdx.x >> 3, ch = blockIdx.x & 7;
    int t = threadIdx.x;
    int h = t >> 8, tg = t & 255;
    __shared__ float wsm[512];
    __shared__ __align__(16) f32x4 red[4][256];
    if (t < 512) wsm[t] = weights[b * NS + ch * 512 + t];
    __syncthreads();
    const f32x4* Ep = (const f32x4*)(E + ((size_t)b * NS + ch * 512 + h * 128) * NE) + tg;
    f32x4 acc; acc[0]=0.f; acc[1]=0.f; acc[2]=0.f; acc[3]=0.f;
    #pragma unroll 4
    for (int s = 0; s < 128; s++){
        f32x4 e = Ep[(size_t)s * 256];
        float w = wsm[h * 128 + s];
        acc[0] += w * e[0]; acc[1] += w * e[1];
        acc[2] += w * e[2]; acc[3] += w * e[3];
    }
    red[h][tg] = acc;
    __syncthreads();
    if (h == 0){
        f32x4 a0 = red[0][tg], a1 = red[1][tg], a2 = red[2][tg], a3 = red[3][tg];
        f32x4 s;
        s[0] = a0[0]+a1[0]+a2[0]+a3[0];
        s[1] = a0[1]+a1[1]+a2[1]+a3[1];
        s[2] = a0[2]+a1[2]+a2[2]+a3[2];
        s[3] = a0[3]+a1[3]+a2[3]+a3[3];
        *(f32x4*)(part + ((size_t)(b * 8 + ch)) * NE + tg * 4) = s;
    }
}

// ---- K5: reduce context partials ----
__global__ __launch_bounds__(256) void k_reduce_ctx(const float* __restrict__ part,
                                                    float* __restrict__ ctx){
    int i = blockIdx.x * 256 + threadIdx.x;  // 32768
    int b = i >> 10, e = i & 1023;
    float s = 0.f;
    #pragma unroll
    for (int ch = 0; ch < 8; ch++) s += part[((size_t)(b * 8 + ch)) * NE + e];
    ctx[i] = s;
}

extern "C" void kernel_launch(void* const* d_in, const int* in_sizes, int n_in,
                              void* d_out, int out_size, void* d_ws, size_t ws_size,
                              hipStream_t stream){
    const float* dec  = (const float*)d_in[0];
    const float* E    = (const float*)d_in[1];
    const int*   mask = (const int*)d_in[2];
    const float* Wh   = (const float*)d_in[3];
    const float* Ws   = (const float*)d_in[4];
    const float* v    = (const float*)d_in[5];
    float* ctx = (float*)d_out;               // (32,1024)
    float* weights = (float*)d_out + NB * NE; // (32,4096)

    char* ws = (char*)d_ws;
    ushort* WTf  = (ushort*)ws;                                     // 1 MB (frag-order W_h)
    float*  part = (float*)ws;                                      // 1 MB ctx partials (after k_scores)
    float*  pdp  = (float*)(ws + (1 << 20));                        // 256 KB proj_dec partials
    float*  scrp = (float*)(ws + (1 << 20) + (256 << 10));          // 1 MB score partials (2 halves)

    k_prep_wtf<<<2048, 256, 0, stream>>>(Wh, WTf);
    k_projdec<<<128, 512, 0, stream>>>(dec, Ws, pdp);
    k_scores<<<1024, 512, 0, stream>>>(E, WTf, pdp, v, scrp);
    k_softmax<<<32, 256, 0, stream>>>(scrp, mask, weights);
    k_context<<<256, 1024, 0, stream>>>(E, weights, part);
    k_reduce_ctx<<<128, 256, 0, stream>>>(part, ctx);
}

// Round 9
// 369.157 us; speedup vs baseline: 1.2635x; 1.2635x over previous
//
#include <hip/hip_runtime.h>
#include <hip/hip_bf16.h>
#include <float.h>
#include <math.h>

#define NB 32
#define NS 4096
#define NE 1024
#define ND 1024
#define NA 512

typedef __attribute__((ext_vector_type(4))) float f32x4;
typedef __attribute__((ext_vector_type(8))) short short8;

static __device__ __forceinline__ ushort f2bf(float f){
    union { float f; unsigned int u; } x; x.f = f;
    unsigned int u = x.u + 0x7fffu + ((x.u >> 16) & 1u);
    return (ushort)(u >> 16);
}

static __device__ __forceinline__ float tanh_fast(float x){
    float e = __expf(2.f * x);
    return 1.f - 2.f / (e + 1.f);
}

// ---- K1a: W_h (1024x512 f32) -> WTf bf16 in MFMA-fragment order ----
// WTf[((s*32 + ng)*64 + lane)*8 + e]  (s = k-slice of 32, ng = n-frag of 16 cols)
//   = Wh[k = s*32 + (lane>>4)*8 + e][col = ng*16 + (lane&15)]
__global__ __launch_bounds__(256) void k_prep_wtf(const float* __restrict__ Wh,
                                                  ushort* __restrict__ WTf){
    int i = blockIdx.x * 256 + threadIdx.x;   // 524288 outputs
    int e = i & 7;
    int lane = (i >> 3) & 63;
    int ng = (i >> 9) & 31;
    int s = i >> 14;
    int k = s * 32 + (lane >> 4) * 8 + e;
    int col = ng * 16 + (lane & 15);
    WTf[i] = f2bf(Wh[k * NA + col]);
}

// ---- K1b: proj_dec partials ----
__global__ __launch_bounds__(512) void k_projdec(const float* __restrict__ dec,
                                                 const float* __restrict__ Ws,
                                                 float* __restrict__ pdp){
    int b = blockIdx.x >> 2, kc = blockIdx.x & 3;
    int a = threadIdx.x;
    const float* dp = dec + b * ND + kc * 256;
    const float* wp = Ws + (size_t)(kc * 256) * NA + a;
    float acc = 0.f;
    #pragma unroll 4
    for (int k = 0; k < 256; k++) acc += dp[k] * wp[(size_t)k * NA];
    pdp[(kc * NB + b) * NA + a] = acc;
}

// ---- K2: fused scores GEMM. BM=128, BN=128 (bn quarter), BK=32, 4 waves (2x2).
// 256 thr, target <=128 total regs -> 4 blocks/CU co-resident (TLP over ILP).
// Writes PARTIAL scores per N-quarter; k_softmax sums 4 partials.
__global__ __launch_bounds__(256, 4) void k_scores(const float* __restrict__ E,
                                                   const ushort* __restrict__ WTf,
                                                   const float* __restrict__ pdp,
                                                   const float* __restrict__ v,
                                                   float* __restrict__ scrp){
    const int t = threadIdx.x;
    const int lane = t & 63, w = t >> 6;
    const int l15 = lane & 15, grp = lane >> 4;
    const int wm = w >> 1, wn = w & 1;

    // XCD-major mapping: 4096 blocks (%8==0, bijective); the 4 bn-quarters of
    // one m-tile are adjacent slots (same XCD -> E-tile L2 reuse).
    const int bid = blockIdx.x;
    const int xcd = bid & 7, slot = bid >> 3;     // 512 slots per XCD
    const int mblk = xcd * 128 + (slot >> 2);     // 0..1023
    const int bn = slot & 3;                      // N-quarter
    const int m0 = mblk << 7;                     // 128-row base
    const int b = mblk >> 5;                      // batch

    __shared__ __align__(16) ushort bft[2][128 * 32];  // 2 x 8KB bf16 E-tiles (swizzled)
    __shared__ float sc[128][2];

    // staging: thread -> row sr = t>>1 (0..127), half = t&1 (16 floats)
    const int sr = t >> 1, half = t & 1;
    const float* gsrc = E + (size_t)(m0 + sr) * NE + half * 16;

    f32x4 acc[4][4];
    f32x4 zero; zero[0]=0.f; zero[1]=0.f; zero[2]=0.f; zero[3]=0.f;
    #pragma unroll
    for (int m = 0; m < 4; m++)
        #pragma unroll
        for (int n = 0; n < 4; n++) acc[m][n] = zero;

    f32x4 st[4];
    auto stage_load = [&](int it){
        const f32x4* p = (const f32x4*)(gsrc + it * 32);
        st[0] = p[0]; st[1] = p[1]; st[2] = p[2]; st[3] = p[3];
    };
    // per row: 32 f32 -> 4 bf16 segs of 16B; thread writes segs half*2, half*2+1
    auto stage_write = [&](int buf){
        short8 h0, h1;
        #pragma unroll
        for (int e = 0; e < 4; e++){
            h0[e]     = (short)__builtin_bit_cast(ushort, __float2bfloat16(st[0][e]));
            h0[e + 4] = (short)__builtin_bit_cast(ushort, __float2bfloat16(st[1][e]));
            h1[e]     = (short)__builtin_bit_cast(ushort, __float2bfloat16(st[2][e]));
            h1[e + 4] = (short)__builtin_bit_cast(ushort, __float2bfloat16(st[3][e]));
        }
        char* bb = (char*)&bft[buf][0];
        unsigned s0 = (unsigned)(half * 2);
        *(short8*)(bb + sr * 64 + (((s0    ) ^ (unsigned)(sr & 3)) << 4)) = h0;
        *(short8*)(bb + sr * 64 + (((s0 + 1) ^ (unsigned)(sr & 3)) << 4)) = h1;
    };

    // B-frag base: ng = bn*8 + wn*4 + n; slice s = it at +it*16384 ushorts
    const ushort* wtf0 = WTf + ((size_t)(bn * 8 + wn * 4) * 64 + lane) * 8;

    // prologue
    stage_load(0);
    stage_write(0);
    asm volatile("s_waitcnt lgkmcnt(0)" ::: "memory");
    __builtin_amdgcn_s_barrier();

    for (int it = 0; it < 32; ++it){
        const int buf = it & 1;
        // 1) B-frag loads (OLDEST in vmem queue this iter)
        short8 wt[4];
        const ushort* wp = wtf0 + (size_t)it * 16384;
        #pragma unroll
        for (int n = 0; n < 4; n++) wt[n] = *(const short8*)(wp + n * 512);
        __builtin_amdgcn_sched_barrier(0);
        // 2) next-tile HBM loads (NEWER; stay in flight through compute)
        if (it < 31) stage_load(it + 1);
        __builtin_amdgcn_sched_barrier(0);
        // 3) compute: 4 ds_read + 16 MFMA (MFMA waits only on wt)
        const char* base = (const char*)&bft[buf][0];
        #pragma unroll
        for (int m = 0; m < 4; m++){
            const int r = wm * 64 + m * 16 + l15;
            short8 af = *(const short8*)(base + r * 64 + (((unsigned)grp ^ (unsigned)(r & 3)) << 4));
            #pragma unroll
            for (int n = 0; n < 4; n++)
                acc[m][n] = __builtin_amdgcn_mfma_f32_16x16x32_bf16(af, wt[n], acc[m][n], 0, 0, 0);
        }
        __builtin_amdgcn_sched_barrier(0);
        // 4) cvt + ds_write next tile (implicit vmcnt wait on st), one barrier
        if (it < 31) stage_write(buf ^ 1);
        asm volatile("s_waitcnt lgkmcnt(0)" ::: "memory");
        __builtin_amdgcn_s_barrier();
    }

    // epilogue: +proj_dec, fast-tanh, v-dot, reduce over this block's 128 cols
    float pdc[4], vc[4];
    #pragma unroll
    for (int n = 0; n < 4; n++){
        int c = bn * 128 + wn * 64 + n * 16 + l15;
        float p = 0.f;
        #pragma unroll
        for (int kc = 0; kc < 4; kc++) p += pdp[(kc * NB + b) * NA + c];
        pdc[n] = p;
        vc[n] = v[c];
    }
    #pragma unroll
    for (int m = 0; m < 4; m++){
        #pragma unroll
        for (int j = 0; j < 4; j++){
            float s = 0.f;
            #pragma unroll
            for (int n = 0; n < 4; n++) s += tanh_fast(acc[m][n][j] + pdc[n]) * vc[n];
            s += __shfl_xor(s, 1);
            s += __shfl_xor(s, 2);
            s += __shfl_xor(s, 4);
            s += __shfl_xor(s, 8);
            if (l15 == 0) sc[wm * 64 + m * 16 + grp * 4 + j][wn] = s;
        }
    }
    __syncthreads();
    if (t < 128)
        scrp[(size_t)bn * (NB * NS) + m0 + t] = sc[t][0] + sc[t][1];
}

// ---- K3: masked softmax; sums the four N-quarter score partials ----
__global__ __launch_bounds__(256) void k_softmax(const float* __restrict__ scrp,
                                                 const int* __restrict__ mask,
                                                 float* __restrict__ weights){
    int b = blockIdx.x, t = threadIdx.x;
    __shared__ float red[8];
    float vals[16];
    float mx = -FLT_MAX;
    #pragma unroll
    for (int i = 0; i < 16; i++){
        int s = i * 256 + t;
        float x = scrp[b * NS + s]
                + scrp[(size_t)(NB * NS) + b * NS + s]
                + scrp[2 * (size_t)(NB * NS) + b * NS + s]
                + scrp[3 * (size_t)(NB * NS) + b * NS + s];
        x = (mask[b * NS + s] != 0) ? x : -FLT_MAX;
        vals[i] = x;
        mx = fmaxf(mx, x);
    }
    #pragma unroll
    for (int off = 32; off; off >>= 1) mx = fmaxf(mx, __shfl_xor(mx, off));
    int wv = t >> 6;
    if ((t & 63) == 0) red[wv] = mx;
    __syncthreads();
    mx = fmaxf(fmaxf(red[0], red[1]), fmaxf(red[2], red[3]));
    float sum = 0.f;
    #pragma unroll
    for (int i = 0; i < 16; i++){ vals[i] = __expf(vals[i] - mx); sum += vals[i]; }
    #pragma unroll
    for (int off = 32; off; off >>= 1) sum += __shfl_xor(sum, off);
    if ((t & 63) == 0) red[4 + wv] = sum;
    __syncthreads();
    sum = red[4] + red[5] + red[6] + red[7];
    float inv = 1.f / sum;
    #pragma unroll
    for (int i = 0; i < 16; i++) weights[b * NS + i * 256 + t] = vals[i] * inv;
}

// ---- K4: context partials over S-chunks ----
__global__ __launch_bounds__(1024) void k_context(const float* __restrict__ E,
                                                  const float* __restrict__ weights,
                                                  float* __restrict__ part){
    int b = blockIdx.x >> 3, ch = blockIdx.x & 7;
    int t = threadIdx.x;
    int h = t >> 8, tg = t & 255;
    __shared__ float wsm[512];
    __shared__ __align__(16) f32x4 red[4][256];
    if (t < 512) wsm[t] = weights[b * NS + ch * 512 + t];
    __syncthreads();
    const f32x4* Ep = (const f32x4*)(E + ((size_t)b * NS + ch * 512 + h * 128) * NE) + tg;
    f32x4 acc; acc[0]=0.f; acc[1]=0.f; acc[2]=0.f; acc[3]=0.f;
    #pragma unroll 4
    for (int s = 0; s < 128; s++){
        f32x4 e = Ep[(size_t)s * 256];
        float w = wsm[h * 128 + s];
        acc[0] += w * e[0]; acc[1] += w * e[1];
        acc[2] += w * e[2]; acc[3] += w * e[3];
    }
    red[h][tg] = acc;
    __syncthreads();
    if (h == 0){
        f32x4 a0 = red[0][tg], a1 = red[1][tg], a2 = red[2][tg], a3 = red[3][tg];
        f32x4 s;
        s[0] = a0[0]+a1[0]+a2[0]+a3[0];
        s[1] = a0[1]+a1[1]+a2[1]+a3[1];
        s[2] = a0[2]+a1[2]+a2[2]+a3[2];
        s[3] = a0[3]+a1[3]+a2[3]+a3[3];
        *(f32x4*)(part + ((size_t)(b * 8 + ch)) * NE + tg * 4) = s;
    }
}

// ---- K5: reduce context partials ----
__global__ __launch_bounds__(256) void k_reduce_ctx(const float* __restrict__ part,
                                                    float* __restrict__ ctx){
    int i = blockIdx.x * 256 + threadIdx.x;  // 32768
    int b = i >> 10, e = i & 1023;
    float s = 0.f;
    #pragma unroll
    for (int ch = 0; ch < 8; ch++) s += part[((size_t)(b * 8 + ch)) * NE + e];
    ctx[i] = s;
}

extern "C" void kernel_launch(void* const* d_in, const int* in_sizes, int n_in,
                              void* d_out, int out_size, void* d_ws, size_t ws_size,
                              hipStream_t stream){
    const float* dec  = (const float*)d_in[0];
    const float* E    = (const float*)d_in[1];
    const int*   mask = (const int*)d_in[2];
    const float* Wh   = (const float*)d_in[3];
    const float* Ws   = (const float*)d_in[4];
    const float* v    = (const float*)d_in[5];
    float* ctx = (float*)d_out;               // (32,1024)
    float* weights = (float*)d_out + NB * NE; // (32,4096)

    char* ws = (char*)d_ws;
    ushort* WTf  = (ushort*)ws;                                     // 1 MB (frag-order W_h)
    float*  part = (float*)ws;                                      // 1 MB ctx partials (after k_scores)
    float*  pdp  = (float*)(ws + (1 << 20));                        // 256 KB proj_dec partials
    float*  scrp = (float*)(ws + (1 << 20) + (256 << 10));          // 2 MB score partials (4 quarters)

    k_prep_wtf<<<2048, 256, 0, stream>>>(Wh, WTf);
    k_projdec<<<128, 512, 0, stream>>>(dec, Ws, pdp);
    k_scores<<<4096, 256, 0, stream>>>(E, WTf, pdp, v, scrp);
    k_softmax<<<32, 256, 0, stream>>>(scrp, mask, weights);
    k_context<<<256, 1024, 0, stream>>>(E, weights, part);
    k_reduce_ctx<<<128, 256, 0, stream>>>(part, ctx);
}